// Round 1
// baseline (4022.255 us; speedup 1.0000x reference)
//
#include <hip/hip_runtime.h>

// 3-layer GCN: h = relu(GCN(x,W1,b1)); h = relu(GCN(h,W2,b2)); h = GCN(h,W3,b3)
// pooled = segment_max(h, batch); out = log_softmax(pooled @ Wl + bl)
//
// GCN agg identity used: with dis[i] = rsqrt(indeg[i]+1),
//   agg[d] = dis[d] * ( sum_{e: dst=d} dis[src_e]*t[src_e]  +  dis[d]*t[d] ) + b
// (self-loop + dst-normalization folded into the elementwise post-pass)
//
// d_ws layout (needs ~103 MB):
//   dis   : N floats (degree -> rsqrt)
//   bufA  : N*128 floats (transform output t)
//   bufB  : N*128 floats (scatter accumulator -> layer output, in place)
//   pooled: G*128 uints (order-preserving-encoded float for atomicMax)

__device__ __forceinline__ unsigned fenc(float x) {
  unsigned b = __float_as_uint(x);
  return (b & 0x80000000u) ? ~b : (b | 0x80000000u);
}
__device__ __forceinline__ float fdec(unsigned k) {
  return (k & 0x80000000u) ? __uint_as_float(k ^ 0x80000000u)
                           : __uint_as_float(~k);
}

__global__ void deg_kernel(const int* __restrict__ dst, float* __restrict__ deg, int E) {
  int e = blockIdx.x * blockDim.x + threadIdx.x;
  if (e < E) atomicAdd(&deg[dst[e]], 1.0f);
}

__global__ void dis_kernel(float* dis, int N) {
  int i = blockIdx.x * blockDim.x + threadIdx.x;
  if (i < N) dis[i] = rsqrtf(dis[i] + 1.0f);  // +1 = self loop; deg>=1 always
}

template <int FIN, int FOUT>
__global__ void transform_kernel(const float* __restrict__ h, const float* __restrict__ W,
                                 float* __restrict__ t, int N) {
  long long tid = (long long)blockIdx.x * blockDim.x + threadIdx.x;
  int n = (int)(tid / FOUT);
  int fo = (int)(tid % FOUT);
  if (n >= N) return;
  float acc = 0.f;
#pragma unroll
  for (int k = 0; k < FIN; ++k) acc += h[(size_t)n * FIN + k] * W[k * FOUT + fo];
  t[(size_t)n * FOUT + fo] = acc;
}

template <int F>
__global__ void agg_kernel(const int* __restrict__ src, const int* __restrict__ dst,
                           const float* __restrict__ dis, const float* __restrict__ t,
                           float* __restrict__ acc, int E) {
  constexpr int TPE = F / 4;  // threads per edge, 4 floats each
  long long tid = (long long)blockIdx.x * blockDim.x + threadIdx.x;
  int e = (int)(tid / TPE);
  if (e >= E) return;
  int off = ((int)(tid % TPE)) * 4;
  int s = src[e];
  int d = dst[e];
  float w = dis[s];
  const float4 v = *reinterpret_cast<const float4*>(t + (size_t)s * F + off);
  float* a = acc + (size_t)d * F + off;
  atomicAdd(a + 0, v.x * w);
  atomicAdd(a + 1, v.y * w);
  atomicAdd(a + 2, v.z * w);
  atomicAdd(a + 3, v.w * w);
}

template <int F, bool RELU>
__global__ void post_kernel(float* __restrict__ acc, const float* __restrict__ t,
                            const float* __restrict__ dis, const float* __restrict__ b, int N) {
  long long tid = (long long)blockIdx.x * blockDim.x + threadIdx.x;
  int n = (int)(tid / F);
  if (n >= N) return;
  int f = (int)(tid % F);
  float di = dis[n];
  float v = di * (acc[tid] + di * t[tid]) + b[f];
  if (RELU) v = fmaxf(v, 0.f);
  acc[tid] = v;  // in-place: acc becomes the layer output
}

__global__ void pool_kernel(const float* __restrict__ h, const int* __restrict__ batch,
                            unsigned* __restrict__ pooled, int N) {
  long long tid = (long long)blockIdx.x * blockDim.x + threadIdx.x;
  int n = (int)(tid >> 7);
  if (n >= N) return;
  int f = (int)(tid & 127);
  atomicMax(&pooled[(size_t)batch[n] * 128 + f], fenc(h[tid]));
}

__global__ void head_kernel(const unsigned* __restrict__ pooled, const float* __restrict__ Wl,
                            const float* __restrict__ bl, float* __restrict__ out, int G) {
  int g = blockIdx.x;
  int t = threadIdx.x;  // 128 threads
  float p = fdec(pooled[(size_t)g * 128 + t]);
  __shared__ float red[128];
  __shared__ float sj[3];
  for (int j = 0; j < 3; ++j) {
    red[t] = p * Wl[t * 3 + j];
    __syncthreads();
    for (int k = 64; k > 0; k >>= 1) {
      if (t < k) red[t] += red[t + k];
      __syncthreads();
    }
    if (t == 0) sj[j] = red[0];
    __syncthreads();
  }
  if (t == 0) {
    float l0 = sj[0] + bl[0], l1 = sj[1] + bl[1], l2 = sj[2] + bl[2];
    float m = fmaxf(l0, fmaxf(l1, l2));
    float lse = logf(expf(l0 - m) + expf(l1 - m) + expf(l2 - m));
    out[g * 3 + 0] = l0 - m - lse;
    out[g * 3 + 1] = l1 - m - lse;
    out[g * 3 + 2] = l2 - m - lse;
  }
}

extern "C" void kernel_launch(void* const* d_in, const int* in_sizes, int n_in,
                              void* d_out, int out_size, void* d_ws, size_t ws_size,
                              hipStream_t stream) {
  const float* x = (const float*)d_in[0];
  const int* ei = (const int*)d_in[1];
  const int* batch = (const int*)d_in[2];
  const float* W1 = (const float*)d_in[3];
  const float* b1 = (const float*)d_in[4];
  const float* W2 = (const float*)d_in[5];
  const float* b2 = (const float*)d_in[6];
  const float* W3 = (const float*)d_in[7];
  const float* b3 = (const float*)d_in[8];
  const float* Wl = (const float*)d_in[9];
  const float* bl = (const float*)d_in[10];
  float* out = (float*)d_out;

  const int N = in_sizes[0] / 2;   // x is [N,2]
  const int E = in_sizes[1] / 2;   // edge_index is [2,E]
  const int G = out_size / 3;      // logits [G,3]

  const int* src = ei;
  const int* dstp = ei + E;

  float* dis = (float*)d_ws;
  size_t NP = ((size_t)N + 255) & ~(size_t)255;
  float* bufA = dis + NP;
  float* bufB = bufA + (size_t)N * 128;
  unsigned* pooled = (unsigned*)(bufB + (size_t)N * 128);

  const int BS = 256;
  auto cdiv = [](long long a, long long b) { return (int)((a + b - 1) / b); };

  // degree -> dis
  hipMemsetAsync(dis, 0, (size_t)N * 4, stream);
  deg_kernel<<<cdiv(E, BS), BS, 0, stream>>>(dstp, dis, E);
  dis_kernel<<<cdiv(N, BS), BS, 0, stream>>>(dis, N);

  // ---- layer 1: [N,2] -> [N,8], relu
  transform_kernel<2, 8><<<cdiv((long long)N * 8, BS), BS, 0, stream>>>(x, W1, bufA, N);
  hipMemsetAsync(bufB, 0, (size_t)N * 8 * 4, stream);
  agg_kernel<8><<<cdiv((long long)E * 2, BS), BS, 0, stream>>>(src, dstp, dis, bufA, bufB, E);
  post_kernel<8, true><<<cdiv((long long)N * 8, BS), BS, 0, stream>>>(bufB, bufA, dis, b1, N);

  // ---- layer 2: [N,8] -> [N,32], relu  (h1 lives in bufB[0..N*8))
  transform_kernel<8, 32><<<cdiv((long long)N * 32, BS), BS, 0, stream>>>(bufB, W2, bufA, N);
  float* acc2 = bufB + (size_t)N * 8;
  hipMemsetAsync(acc2, 0, (size_t)N * 32 * 4, stream);
  agg_kernel<32><<<cdiv((long long)E * 8, BS), BS, 0, stream>>>(src, dstp, dis, bufA, acc2, E);
  post_kernel<32, true><<<cdiv((long long)N * 32, BS), BS, 0, stream>>>(acc2, bufA, dis, b2, N);

  // ---- layer 3: [N,32] -> [N,128], no relu  (h2 lives in acc2)
  transform_kernel<32, 128><<<cdiv((long long)N * 128, BS), BS, 0, stream>>>(acc2, W3, bufA, N);
  hipMemsetAsync(bufB, 0, (size_t)N * 128 * 4, stream);  // h2 dead after transform
  agg_kernel<128><<<cdiv((long long)E * 32, BS), BS, 0, stream>>>(src, dstp, dis, bufA, bufB, E);
  post_kernel<128, false><<<cdiv((long long)N * 128, BS), BS, 0, stream>>>(bufB, bufA, dis, b3, N);

  // ---- global max pool + head
  hipMemsetAsync(pooled, 0, (size_t)G * 128 * 4, stream);  // fenc key 0 == -NaN sentinel (below -inf)
  pool_kernel<<<cdiv((long long)N * 128, BS), BS, 0, stream>>>(bufB, batch, pooled, N);
  head_kernel<<<G, 128, 0, stream>>>(pooled, Wl, bl, out, G);
}

// Round 2
// 737.426 us; speedup vs baseline: 5.4544x; 5.4544x over previous
//
#include <hip/hip_runtime.h>

// 3-layer GCN via CSR gather (no float scatter-atomics).
//
// agg[d] = dis[d] * ( sum_{e: dst=d} dis[src_e]*t[src_e] + dis[d]*t[d] ) + b
// with dis[i] = rsqrt(indeg[i]+1)  (self-loop + dst-norm folded into gather epilogue)
//
// d_ws layout (~110 MB):
//   deg/dis : N ints -> N floats (in place)
//   rp      : N+1 ints (CSR row pointers, by dst)
//   csr     : E ints (src node ids, grouped by dst)
//   bufA    : N*128 floats (transform output t; its head doubles as scatter cursor pre-layers)
//   bufB    : N*128 floats (h1 | h2 | final h3)
//   pooled  : G*128 uints
//   sums    : scan partials

__device__ __forceinline__ unsigned fenc(float x) {
  unsigned b = __float_as_uint(x);
  return (b & 0x80000000u) ? ~b : (b | 0x80000000u);
}
__device__ __forceinline__ float fdec(unsigned k) {
  return (k & 0x80000000u) ? __uint_as_float(k ^ 0x80000000u)
                           : __uint_as_float(~k);
}

// ---------------- CSR build ----------------

__global__ void deg_int_kernel(const int* __restrict__ dst, int* __restrict__ deg, int E) {
  int e = blockIdx.x * blockDim.x + threadIdx.x;
  if (e < E) atomicAdd(&deg[dst[e]], 1);
}

// inclusive scan of 256-element tiles; out[i+1] = tile-local inclusive
__global__ void scan_tile_kernel(const int* __restrict__ in, int* __restrict__ out,
                                 int* __restrict__ sums, int n) {
  __shared__ int s[256];
  int i = blockIdx.x * 256 + threadIdx.x;
  s[threadIdx.x] = (i < n) ? in[i] : 0;
  __syncthreads();
  for (int o = 1; o < 256; o <<= 1) {
    int t = (threadIdx.x >= o) ? s[threadIdx.x - o] : 0;
    __syncthreads();
    s[threadIdx.x] += t;
    __syncthreads();
  }
  if (i < n) out[i + 1] = s[threadIdx.x];
  if (threadIdx.x == 255) sums[blockIdx.x] = s[255];
}

__global__ void scan_sums_kernel(int* __restrict__ sums, int ntiles) {
  __shared__ int s[1024];
  int t = threadIdx.x;
  s[t] = (t < ntiles) ? sums[t] : 0;
  __syncthreads();
  for (int o = 1; o < 1024; o <<= 1) {
    int v = (t >= o) ? s[t - o] : 0;
    __syncthreads();
    s[t] += v;
    __syncthreads();
  }
  if (t < ntiles) sums[t] = s[t];
}

__global__ void scan_add_kernel(int* __restrict__ out, const int* __restrict__ sums, int n) {
  int i = blockIdx.x * 256 + threadIdx.x;
  if (i < n) {
    if (blockIdx.x > 0) out[i + 1] += sums[blockIdx.x - 1];
    if (i == 0) out[0] = 0;
  }
}

__global__ void dis_kernel(float* dis, const int* deg_alias_unused, int N) {
  int i = blockIdx.x * blockDim.x + threadIdx.x;
  if (i < N) {
    int d = ((const int*)dis)[i];
    dis[i] = rsqrtf((float)d + 1.0f);
  }
}

__global__ void cursor_copy_kernel(int* __restrict__ cursor, const int* __restrict__ rp, int N) {
  int i = blockIdx.x * blockDim.x + threadIdx.x;
  if (i < N) cursor[i] = rp[i];
}

__global__ void scatter_kernel(const int* __restrict__ src, const int* __restrict__ dst,
                               int* __restrict__ cursor, int* __restrict__ csr, int E) {
  int e = blockIdx.x * blockDim.x + threadIdx.x;
  if (e < E) {
    int pos = atomicAdd(&cursor[dst[e]], 1);
    csr[pos] = src[e];
  }
}

// ---------------- dense transform (LDS-staged input rows) ----------------

template <int FIN, int FOUT>
__global__ void transform_kernel(const float* __restrict__ h, const float* __restrict__ W,
                                 float* __restrict__ t, int N) {
  constexpr int NPB = 256 / FOUT;  // nodes per block
  __shared__ float hs[NPB * FIN];
  int nb = blockIdx.x * NPB;
  for (int i = threadIdx.x; i < NPB * FIN; i += 256) {
    int nn = nb + i / FIN;
    hs[i] = (nn < N) ? h[(size_t)nb * FIN + i] : 0.f;
  }
  __syncthreads();
  int nl = threadIdx.x / FOUT;
  int fo = threadIdx.x % FOUT;
  int n = nb + nl;
  if (n >= N) return;
  float acc = 0.f;
#pragma unroll
  for (int k = 0; k < FIN; ++k) acc += hs[nl * FIN + k] * W[k * FOUT + fo];
  t[(size_t)n * FOUT + fo] = acc;
}

// ---------------- fused gather-aggregate + norm + bias + relu ----------------

template <int F, bool RELU>
__global__ void gcn_gather_kernel(const int* __restrict__ rp, const int* __restrict__ csr,
                                  const float* __restrict__ dis, const float* __restrict__ t,
                                  const float* __restrict__ b, float* __restrict__ out, int N) {
  int tid = blockIdx.x * blockDim.x + threadIdx.x;
  int n = tid / F;
  if (n >= N) return;
  int f = tid % F;
  int j0 = rp[n], j1 = rp[n + 1];
  float din = dis[n];
  float acc = din * t[(size_t)n * F + f];  // self loop
  for (int j = j0; j < j1; ++j) {
    int s = csr[j];
    acc += dis[s] * t[(size_t)s * F + f];
  }
  float v = din * acc + b[f];
  if (RELU) v = fmaxf(v, 0.f);
  out[(size_t)n * F + f] = v;
}

// ---------------- pooling (batch sorted -> segmented max, few atomics) ----------------

__global__ void pool_kernel(const float* __restrict__ h, const int* __restrict__ batch,
                            unsigned* __restrict__ pooled, int N) {
  int per = (N + gridDim.x - 1) / gridDim.x;
  int s = blockIdx.x * per;
  int e = min(N, s + per);
  if (s >= e) return;
  int f = threadIdx.x;  // 128
  int cur = batch[s];
  float v = -INFINITY;
  for (int n = s; n < e; ++n) {
    int g = batch[n];
    if (g != cur) {
      atomicMax(&pooled[(size_t)cur * 128 + f], fenc(v));
      cur = g;
      v = -INFINITY;
    }
    v = fmaxf(v, h[(size_t)n * 128 + f]);
  }
  atomicMax(&pooled[(size_t)cur * 128 + f], fenc(v));
}

__global__ void head_kernel(const unsigned* __restrict__ pooled, const float* __restrict__ Wl,
                            const float* __restrict__ bl, float* __restrict__ out, int G) {
  int g = blockIdx.x;
  int t = threadIdx.x;  // 128 threads
  float p = fdec(pooled[(size_t)g * 128 + t]);
  __shared__ float red[128];
  __shared__ float sj[3];
  for (int j = 0; j < 3; ++j) {
    red[t] = p * Wl[t * 3 + j];
    __syncthreads();
    for (int k = 64; k > 0; k >>= 1) {
      if (t < k) red[t] += red[t + k];
      __syncthreads();
    }
    if (t == 0) sj[j] = red[0];
    __syncthreads();
  }
  if (t == 0) {
    float l0 = sj[0] + bl[0], l1 = sj[1] + bl[1], l2 = sj[2] + bl[2];
    float m = fmaxf(l0, fmaxf(l1, l2));
    float lse = logf(expf(l0 - m) + expf(l1 - m) + expf(l2 - m));
    out[g * 3 + 0] = l0 - m - lse;
    out[g * 3 + 1] = l1 - m - lse;
    out[g * 3 + 2] = l2 - m - lse;
  }
}

extern "C" void kernel_launch(void* const* d_in, const int* in_sizes, int n_in,
                              void* d_out, int out_size, void* d_ws, size_t ws_size,
                              hipStream_t stream) {
  const float* x = (const float*)d_in[0];
  const int* ei = (const int*)d_in[1];
  const int* batch = (const int*)d_in[2];
  const float* W1 = (const float*)d_in[3];
  const float* b1 = (const float*)d_in[4];
  const float* W2 = (const float*)d_in[5];
  const float* b2 = (const float*)d_in[6];
  const float* W3 = (const float*)d_in[7];
  const float* b3 = (const float*)d_in[8];
  const float* Wl = (const float*)d_in[9];
  const float* bl = (const float*)d_in[10];
  float* out = (float*)d_out;

  const int N = in_sizes[0] / 2;  // x [N,2]
  const int E = in_sizes[1] / 2;  // edge_index [2,E]
  const int G = out_size / 3;     // logits [G,3]

  const int* src = ei;
  const int* dstp = ei + E;

  size_t NP = ((size_t)N + 256) & ~(size_t)255;  // >= N+1, 256-aligned
  size_t EP = ((size_t)E + 255) & ~(size_t)255;

  float* dis = (float*)d_ws;                       // N (int deg -> float dis in place)
  int* rp = (int*)d_ws + NP;                       // N+1
  int* csr = rp + NP;                              // E
  float* bufA = (float*)(csr + EP);                // N*128 (t); head reused as cursor pre-layers
  float* bufB = bufA + (size_t)N * 128;            // N*128 (h1 | h2 | h3)
  unsigned* pooled = (unsigned*)(bufB + (size_t)N * 128);  // G*128
  int* sums = (int*)(pooled + (size_t)G * 128);    // scan partials
  int* cursor = (int*)bufA;

  const int BS = 256;
  auto cdiv = [](long long a, long long b) { return (int)((a + b - 1) / b); };
  int ntiles = cdiv(N, 256);

  // ---- CSR build
  hipMemsetAsync(dis, 0, (size_t)N * 4, stream);  // deg = 0
  deg_int_kernel<<<cdiv(E, BS), BS, 0, stream>>>(dstp, (int*)dis, E);
  scan_tile_kernel<<<ntiles, 256, 0, stream>>>((int*)dis, rp, sums, N);
  scan_sums_kernel<<<1, 1024, 0, stream>>>(sums, ntiles);
  scan_add_kernel<<<ntiles, 256, 0, stream>>>(rp, sums, N);
  dis_kernel<<<cdiv(N, BS), BS, 0, stream>>>(dis, nullptr, N);  // deg -> rsqrt(deg+1)
  cursor_copy_kernel<<<cdiv(N, BS), BS, 0, stream>>>(cursor, rp, N);
  scatter_kernel<<<cdiv(E, BS), BS, 0, stream>>>(src, dstp, cursor, csr, E);

  float* h1 = bufB;                       // N*8
  float* h2 = bufB + (size_t)N * 8;       // N*32
  float* h3 = bufB;                       // N*128 (h1/h2 dead by then)

  // ---- layer 1: [N,2] -> [N,8], relu
  transform_kernel<2, 8><<<cdiv(N, 32), 256, 0, stream>>>(x, W1, bufA, N);
  gcn_gather_kernel<8, true><<<cdiv((long long)N * 8, BS), BS, 0, stream>>>(rp, csr, dis, bufA, b1, h1, N);

  // ---- layer 2: [N,8] -> [N,32], relu
  transform_kernel<8, 32><<<cdiv(N, 8), 256, 0, stream>>>(h1, W2, bufA, N);
  gcn_gather_kernel<32, true><<<cdiv((long long)N * 32, BS), BS, 0, stream>>>(rp, csr, dis, bufA, b2, h2, N);

  // ---- layer 3: [N,32] -> [N,128]
  transform_kernel<32, 128><<<cdiv(N, 2), 256, 0, stream>>>(h2, W3, bufA, N);
  gcn_gather_kernel<128, false><<<cdiv((long long)N * 128, BS), BS, 0, stream>>>(rp, csr, dis, bufA, b3, h3, N);

  // ---- pool + head
  hipMemsetAsync(pooled, 0, (size_t)G * 128 * 4, stream);
  pool_kernel<<<512, 128, 0, stream>>>(h3, batch, pooled, N);
  head_kernel<<<G, 128, 0, stream>>>(pooled, Wl, bl, out, G);
}

// Round 3
// 406.518 us; speedup vs baseline: 9.8944x; 1.8140x over previous
//
#include <hip/hip_runtime.h>

// 3-layer GCN, aggregation done in the INPUT dim of each layer (A(XW) = (AX)W):
//   a1 = A_norm x        (F=2)   ; h1s = dis * relu(a1 W1 + b1)   [N,8]  (pre-scaled)
//   a2 = dis*(h1s_self + sum h1s[nbr])  (F=8)  ; h2s = dis * relu(a2 W2 + b2) [N,32]
//   a3 = ... (F=32)      ; h3 = a3 W3 + b3  [N,128]
//   pooled = segment_max(h3), out = log_softmax(pooled Wl + bl)
//
// Pre-scaling trick: store ts = dis[n]*h[n]; then A_norm h [d] = dis[d]*(ts[d] + sum ts[s])
// -> gather inner loop is a pure accumulate (no per-edge dis load).

__device__ __forceinline__ unsigned fenc(float x) {
  unsigned b = __float_as_uint(x);
  return (b & 0x80000000u) ? ~b : (b | 0x80000000u);
}
__device__ __forceinline__ float fdec(unsigned k) {
  return (k & 0x80000000u) ? __uint_as_float(k ^ 0x80000000u)
                           : __uint_as_float(~k);
}

// ---------------- CSR build ----------------

__global__ void deg_int_kernel(const int* __restrict__ dst, int* __restrict__ deg, int E) {
  int e = blockIdx.x * blockDim.x + threadIdx.x;
  if (e < E) atomicAdd(&deg[dst[e]], 1);
}

__global__ void scan_tile_kernel(const int* __restrict__ in, int* __restrict__ out,
                                 int* __restrict__ sums, int n) {
  __shared__ int s[256];
  int i = blockIdx.x * 256 + threadIdx.x;
  s[threadIdx.x] = (i < n) ? in[i] : 0;
  __syncthreads();
  for (int o = 1; o < 256; o <<= 1) {
    int t = (threadIdx.x >= o) ? s[threadIdx.x - o] : 0;
    __syncthreads();
    s[threadIdx.x] += t;
    __syncthreads();
  }
  if (i < n) out[i + 1] = s[threadIdx.x];
  if (threadIdx.x == 255) sums[blockIdx.x] = s[255];
}

__global__ void scan_sums_kernel(int* __restrict__ sums, int ntiles) {
  __shared__ int s[1024];
  int t = threadIdx.x;
  s[t] = (t < ntiles) ? sums[t] : 0;
  __syncthreads();
  for (int o = 1; o < 1024; o <<= 1) {
    int v = (t >= o) ? s[t - o] : 0;
    __syncthreads();
    s[t] += v;
    __syncthreads();
  }
  if (t < ntiles) sums[t] = s[t];
}

__global__ void scan_add_kernel(int* __restrict__ out, const int* __restrict__ sums, int n) {
  int i = blockIdx.x * 256 + threadIdx.x;
  if (i < n) {
    if (blockIdx.x > 0) out[i + 1] += sums[blockIdx.x - 1];
    if (i == 0) out[0] = 0;
  }
}

__global__ void dis_kernel(float* dis, int N) {
  int i = blockIdx.x * blockDim.x + threadIdx.x;
  if (i < N) {
    int d = ((const int*)dis)[i];
    dis[i] = rsqrtf((float)d + 1.0f);
  }
}

__global__ void cursor_copy_kernel(int* __restrict__ cursor, const int* __restrict__ rp, int N) {
  int i = blockIdx.x * blockDim.x + threadIdx.x;
  if (i < N) cursor[i] = rp[i];
}

__global__ void scatter_kernel(const int* __restrict__ src, const int* __restrict__ dst,
                               int* __restrict__ cursor, int* __restrict__ csr, int E) {
  int e = blockIdx.x * blockDim.x + threadIdx.x;
  if (e < E) {
    int pos = atomicAdd(&cursor[dst[e]], 1);
    csr[pos] = src[e];
  }
}

// ---------------- aggregation (gather) ----------------

// F=2, thread-per-node, x unscaled -> a1 = dis[n]*(sum dis[s]x[s] + dis[n]x[n])
__global__ void agg2_kernel(const int* __restrict__ rp, const int* __restrict__ csr,
                            const float* __restrict__ dis, const float* __restrict__ x,
                            float* __restrict__ a1, int N) {
  int n = blockIdx.x * blockDim.x + threadIdx.x;
  if (n >= N) return;
  float dn = dis[n];
  float2 xn = *reinterpret_cast<const float2*>(x + 2 * (size_t)n);
  float ax = dn * xn.x, ay = dn * xn.y;
  int j0 = rp[n], j1 = rp[n + 1];
#pragma unroll 4
  for (int j = j0; j < j1; ++j) {
    int s = csr[j];
    float w = dis[s];
    float2 xs = *reinterpret_cast<const float2*>(x + 2 * (size_t)s);
    ax += w * xs.x;
    ay += w * xs.y;
  }
  a1[2 * (size_t)n] = dn * ax;
  a1[2 * (size_t)n + 1] = dn * ay;
}

// F in {8,32}, F/4 threads per node, ts pre-scaled by dis -> out = dis[n]*(ts[n]+sum ts[s])
template <int F>
__global__ void agg_vec_kernel(const int* __restrict__ rp, const int* __restrict__ csr,
                               const float* __restrict__ dis, const float* __restrict__ ts,
                               float* __restrict__ outp, int N) {
  constexpr int TPN = F / 4;
  int tid = blockIdx.x * blockDim.x + threadIdx.x;
  int n = tid / TPN;
  if (n >= N) return;
  int off = (tid % TPN) * 4;
  float4 acc = *reinterpret_cast<const float4*>(ts + (size_t)n * F + off);  // self term
  int j0 = rp[n], j1 = rp[n + 1];
#pragma unroll 4
  for (int j = j0; j < j1; ++j) {
    int s = csr[j];
    const float4 v = *reinterpret_cast<const float4*>(ts + (size_t)s * F + off);
    acc.x += v.x;
    acc.y += v.y;
    acc.z += v.z;
    acc.w += v.w;
  }
  float dn = dis[n];
  float4 o;
  o.x = dn * acc.x;
  o.y = dn * acc.y;
  o.z = dn * acc.z;
  o.w = dn * acc.w;
  *reinterpret_cast<float4*>(outp + (size_t)n * F + off) = o;
}

// ---------------- dense transform + bias (+relu) (+dis pre-scale) ----------------

template <int FIN, int FOUT, bool RELU, bool SCALE>
__global__ void mlp_kernel(const float* __restrict__ h, const float* __restrict__ W,
                           const float* __restrict__ b, const float* __restrict__ dis,
                           float* __restrict__ t, int N) {
  constexpr int NPB = 256 / FOUT;  // nodes per block
  __shared__ float hs[NPB * FIN];
  int nb = blockIdx.x * NPB;
  for (int i = threadIdx.x; i < NPB * FIN; i += 256) {
    int nn = nb + i / FIN;
    hs[i] = (nn < N) ? h[(size_t)nb * FIN + i] : 0.f;
  }
  __syncthreads();
  int nl = threadIdx.x / FOUT;
  int fo = threadIdx.x % FOUT;
  int n = nb + nl;
  if (n >= N) return;
  float acc = b[fo];
#pragma unroll
  for (int k = 0; k < FIN; ++k) acc += hs[nl * FIN + k] * W[k * FOUT + fo];
  if (RELU) acc = fmaxf(acc, 0.f);
  if (SCALE) acc *= dis[n];
  t[(size_t)n * FOUT + fo] = acc;
}

// ---------------- pooling + head ----------------

__global__ void pool_kernel(const float* __restrict__ h, const int* __restrict__ batch,
                            unsigned* __restrict__ pooled, int N) {
  int per = (N + gridDim.x - 1) / gridDim.x;
  int s = blockIdx.x * per;
  int e = min(N, s + per);
  if (s >= e) return;
  int f = threadIdx.x;  // 128
  int cur = batch[s];
  float v = -INFINITY;
  for (int n = s; n < e; ++n) {
    int g = batch[n];
    if (g != cur) {
      atomicMax(&pooled[(size_t)cur * 128 + f], fenc(v));
      cur = g;
      v = -INFINITY;
    }
    v = fmaxf(v, h[(size_t)n * 128 + f]);
  }
  atomicMax(&pooled[(size_t)cur * 128 + f], fenc(v));
}

__global__ void head_kernel(const unsigned* __restrict__ pooled, const float* __restrict__ Wl,
                            const float* __restrict__ bl, float* __restrict__ out, int G) {
  int g = blockIdx.x;
  int t = threadIdx.x;  // 128 threads
  float p = fdec(pooled[(size_t)g * 128 + t]);
  __shared__ float red[128];
  __shared__ float sj[3];
  for (int j = 0; j < 3; ++j) {
    red[t] = p * Wl[t * 3 + j];
    __syncthreads();
    for (int k = 64; k > 0; k >>= 1) {
      if (t < k) red[t] += red[t + k];
      __syncthreads();
    }
    if (t == 0) sj[j] = red[0];
    __syncthreads();
  }
  if (t == 0) {
    float l0 = sj[0] + bl[0], l1 = sj[1] + bl[1], l2 = sj[2] + bl[2];
    float m = fmaxf(l0, fmaxf(l1, l2));
    float lse = logf(expf(l0 - m) + expf(l1 - m) + expf(l2 - m));
    out[g * 3 + 0] = l0 - m - lse;
    out[g * 3 + 1] = l1 - m - lse;
    out[g * 3 + 2] = l2 - m - lse;
  }
}

extern "C" void kernel_launch(void* const* d_in, const int* in_sizes, int n_in,
                              void* d_out, int out_size, void* d_ws, size_t ws_size,
                              hipStream_t stream) {
  const float* x = (const float*)d_in[0];
  const int* ei = (const int*)d_in[1];
  const int* batch = (const int*)d_in[2];
  const float* W1 = (const float*)d_in[3];
  const float* b1 = (const float*)d_in[4];
  const float* W2 = (const float*)d_in[5];
  const float* b2 = (const float*)d_in[6];
  const float* W3 = (const float*)d_in[7];
  const float* b3 = (const float*)d_in[8];
  const float* Wl = (const float*)d_in[9];
  const float* bl = (const float*)d_in[10];
  float* out = (float*)d_out;

  const int N = in_sizes[0] / 2;  // x [N,2]
  const int E = in_sizes[1] / 2;  // edge_index [2,E]
  const int G = out_size / 3;     // logits [G,3]

  const int* src = ei;
  const int* dstp = ei + E;

  size_t NP = ((size_t)N + 256) & ~(size_t)255;  // >= N+1, 256-aligned
  size_t EP = ((size_t)E + 255) & ~(size_t)255;

  float* dis = (float*)d_ws;           // N (int deg -> float dis in place)
  int* rp = (int*)d_ws + NP;           // N+1
  int* csr = rp + NP;                  // E
  float* arena = (float*)(csr + EP);

  float* a1 = arena;                         // N*2
  float* a2 = arena + (size_t)2 * N;         // N*8
  float* a3 = arena + (size_t)10 * N;        // N*32
  float* h1s = arena + (size_t)42 * N;       // N*8   (dis-scaled)
  float* h2s = arena + (size_t)50 * N;       // N*32  (dis-scaled)
  float* h3 = arena + (size_t)82 * N;        // N*128
  unsigned* pooled = (unsigned*)(arena + (size_t)210 * N);  // G*128
  int* sums = (int*)(pooled + (size_t)G * 128);             // scan partials
  int* cursor = (int*)a1;  // dead before a1 is written

  const int BS = 256;
  auto cdiv = [](long long a, long long b) { return (int)((a + b - 1) / b); };
  int ntiles = cdiv(N, 256);

  // ---- CSR build
  hipMemsetAsync(dis, 0, (size_t)N * 4, stream);  // deg = 0
  deg_int_kernel<<<cdiv(E, BS), BS, 0, stream>>>(dstp, (int*)dis, E);
  scan_tile_kernel<<<ntiles, 256, 0, stream>>>((int*)dis, rp, sums, N);
  scan_sums_kernel<<<1, 1024, 0, stream>>>(sums, ntiles);
  scan_add_kernel<<<ntiles, 256, 0, stream>>>(rp, sums, N);
  dis_kernel<<<cdiv(N, BS), BS, 0, stream>>>(dis, N);  // deg -> rsqrt(deg+1)
  cursor_copy_kernel<<<cdiv(N, BS), BS, 0, stream>>>(cursor, rp, N);
  scatter_kernel<<<cdiv(E, BS), BS, 0, stream>>>(src, dstp, cursor, csr, E);

  // ---- layer 1: agg(F=2) then 2->8 relu, dis-scaled
  agg2_kernel<<<cdiv(N, BS), BS, 0, stream>>>(rp, csr, dis, x, a1, N);
  mlp_kernel<2, 8, true, true><<<cdiv(N, 32), 256, 0, stream>>>(a1, W1, b1, dis, h1s, N);

  // ---- layer 2: agg(F=8) then 8->32 relu, dis-scaled
  agg_vec_kernel<8><<<cdiv((long long)N * 2, BS), BS, 0, stream>>>(rp, csr, dis, h1s, a2, N);
  mlp_kernel<8, 32, true, true><<<cdiv(N, 8), 256, 0, stream>>>(a2, W2, b2, dis, h2s, N);

  // ---- layer 3: agg(F=32) then 32->128 (no relu, unscaled)
  agg_vec_kernel<32><<<cdiv((long long)N * 8, BS), BS, 0, stream>>>(rp, csr, dis, h2s, a3, N);
  mlp_kernel<32, 128, false, false><<<cdiv(N, 2), 256, 0, stream>>>(a3, W3, b3, dis, h3, N);

  // ---- pool + head
  hipMemsetAsync(pooled, 0, (size_t)G * 128 * 4, stream);
  pool_kernel<<<512, 128, 0, stream>>>(h3, batch, pooled, N);
  head_kernel<<<G, 128, 0, stream>>>(pooled, Wl, bl, out, G);
}

// Round 4
// 164.201 us; speedup vs baseline: 24.4960x; 2.4757x over previous
//
#include <hip/hip_runtime.h>

// 3-layer GCN, input-dim aggregation (A(XW) = (AX)W), bucketed CSR build.
//
//   a1 = A_norm x (F=2); h1s = dis*relu(a1 W1+b1)        [N,8]
//   a2 = dis*(h1s + sum_nbr h1s) (F=8); h2s = dis*relu(a2 W2+b2) [N,32]
//   a3 = ... (F=32); h3 = a3 W3 + b3 fused with segment_max -> pooled
//   out = log_softmax(pooled Wl + bl)
//
// CSR build: counting-sort edges by dst in 512-node buckets.
//   p1: bucket histogram + scan (bucket bases)
//   p2: partition edges into buckets, LDS-ordered so global writes coalesce
//   p3: per-bucket (one block) local histogram -> dis, rp; local scatter -> csr
//       (csr region per block is exclusive + L2-resident -> ~6.4MB writeback,
//        vs 102MB for the naive random scatter in R3)

#define BSHIFT 9
#define BSZ 512       // nodes per bucket
#define P2_TILE 4096

__device__ __forceinline__ unsigned fenc(float x) {
  unsigned b = __float_as_uint(x);
  return (b & 0x80000000u) ? ~b : (b | 0x80000000u);
}
__device__ __forceinline__ float fdec(unsigned k) {
  return (k & 0x80000000u) ? __uint_as_float(k ^ 0x80000000u)
                           : __uint_as_float(~k);
}

// ---------------- CSR build ----------------

__global__ void p1_hist_kernel(const int* __restrict__ dst, int* __restrict__ bucketCount, int E) {
  __shared__ int h[256];
  h[threadIdx.x] = 0;
  __syncthreads();
  for (int e = blockIdx.x * blockDim.x + threadIdx.x; e < E; e += gridDim.x * blockDim.x)
    atomicAdd(&h[dst[e] >> BSHIFT], 1);
  __syncthreads();
  if (h[threadIdx.x] > 0) atomicAdd(&bucketCount[threadIdx.x], h[threadIdx.x]);
}

__global__ void p1_scan_kernel(const int* __restrict__ bucketCount, int* __restrict__ bucketBase,
                               int* __restrict__ bucketCursor, int B, int E) {
  __shared__ int s[256];
  int t = threadIdx.x;
  int v = (t < B) ? bucketCount[t] : 0;
  s[t] = v;
  __syncthreads();
  for (int o = 1; o < 256; o <<= 1) {
    int u = (t >= o) ? s[t - o] : 0;
    __syncthreads();
    s[t] += u;
    __syncthreads();
  }
  int excl = s[t] - v;
  bucketBase[t] = excl;          // for t>=B this equals E (harmless)
  bucketCursor[t] = excl;
  if (t == 0) bucketBase[256] = E;
}

// partition edges into bucket-contiguous array `part`, packed (dstl<<17)|src.
// LDS-reorders each 4096-edge tile so global writes are run-coalesced.
__global__ __launch_bounds__(256) void p2_partition_kernel(
    const int* __restrict__ src, const int* __restrict__ dst,
    int* __restrict__ bucketCursor, unsigned* __restrict__ part, int E) {
  __shared__ int hist[256];
  __shared__ int lbase[256];
  __shared__ int gbase[256];
  __shared__ int cur[256];
  __shared__ unsigned sbuf[P2_TILE];
  __shared__ unsigned abuf[P2_TILE];
  int t = threadIdx.x;
  int e0 = blockIdx.x * P2_TILE;
  int cnt = min(P2_TILE, E - e0);

  hist[t] = 0;
  __syncthreads();

  int myb[16];
  unsigned myp[16];
#pragma unroll
  for (int k = 0; k < 16; ++k) {
    int i = t + k * 256;
    if (i < cnt) {
      int e = e0 + i;
      int d = dst[e];
      int b = d >> BSHIFT;
      myb[k] = b;
      myp[k] = ((unsigned)(d & (BSZ - 1)) << 17) | (unsigned)src[e];
      atomicAdd(&hist[b], 1);
    } else {
      myb[k] = -1;
      myp[k] = 0;
    }
  }
  __syncthreads();

  // exclusive scan of hist -> lbase
  int v = hist[t];
  lbase[t] = v;
  __syncthreads();
  for (int o = 1; o < 256; o <<= 1) {
    int u = (t >= o) ? lbase[t - o] : 0;
    __syncthreads();
    lbase[t] += u;
    __syncthreads();
  }
  int excl = lbase[t] - v;
  __syncthreads();
  lbase[t] = excl;
  if (v > 0) gbase[t] = atomicAdd(&bucketCursor[t], v);
  cur[t] = 0;
  __syncthreads();

#pragma unroll
  for (int k = 0; k < 16; ++k) {
    int b = myb[k];
    if (b >= 0) {
      int pos = atomicAdd(&cur[b], 1);
      int li = lbase[b] + pos;
      sbuf[li] = myp[k];
      abuf[li] = (unsigned)(gbase[b] + pos);
    }
  }
  __syncthreads();

#pragma unroll
  for (int k = 0; k < 16; ++k) {
    int i = t + k * 256;
    if (i < cnt) part[abuf[i]] = sbuf[i];
  }
}

// one block per bucket: local deg hist -> dis, rp; local scatter -> csr
__global__ __launch_bounds__(512) void p3_build_kernel(
    const unsigned* __restrict__ part, const int* __restrict__ bucketBase,
    float* __restrict__ dis, int* __restrict__ rp, int* __restrict__ csr,
    int N, int B, int E) {
  __shared__ int hist[BSZ];
  __shared__ int scn[BSZ];
  int b = blockIdx.x, t = threadIdx.x;
  int base = bucketBase[b], end = bucketBase[b + 1];
  int cnt = end - base;

  hist[t] = 0;
  __syncthreads();
  for (int i = t; i < cnt; i += BSZ) atomicAdd(&hist[part[base + i] >> 17], 1);
  __syncthreads();

  int v = hist[t];
  scn[t] = v;
  __syncthreads();
  for (int o = 1; o < BSZ; o <<= 1) {
    int u = (t >= o) ? scn[t - o] : 0;
    __syncthreads();
    scn[t] += u;
    __syncthreads();
  }
  int excl = scn[t] - v;

  int n = (b << BSHIFT) + t;
  if (n < N) {
    dis[n] = rsqrtf((float)v + 1.0f);
    rp[n] = base + excl;
  }
  if (b == B - 1 && t == 0) rp[N] = E;

  hist[t] = excl;  // reuse as cursor
  __syncthreads();
  for (int i = t; i < cnt; i += BSZ) {
    unsigned p = part[base + i];
    int pos = atomicAdd(&hist[p >> 17], 1);
    csr[base + pos] = (int)(p & 0x1FFFFu);
  }
}

// ---------------- aggregation (gather) ----------------

__global__ void agg2_kernel(const int* __restrict__ rp, const int* __restrict__ csr,
                            const float* __restrict__ dis, const float* __restrict__ x,
                            float* __restrict__ a1, int N) {
  int n = blockIdx.x * blockDim.x + threadIdx.x;
  if (n >= N) return;
  float dn = dis[n];
  float2 xn = *reinterpret_cast<const float2*>(x + 2 * (size_t)n);
  float ax = dn * xn.x, ay = dn * xn.y;
  int j0 = rp[n], j1 = rp[n + 1];
#pragma unroll 4
  for (int j = j0; j < j1; ++j) {
    int s = csr[j];
    float w = dis[s];
    float2 xs = *reinterpret_cast<const float2*>(x + 2 * (size_t)s);
    ax += w * xs.x;
    ay += w * xs.y;
  }
  a1[2 * (size_t)n] = dn * ax;
  a1[2 * (size_t)n + 1] = dn * ay;
}

template <int F>
__global__ void agg_vec_kernel(const int* __restrict__ rp, const int* __restrict__ csr,
                               const float* __restrict__ dis, const float* __restrict__ ts,
                               float* __restrict__ outp, int N) {
  constexpr int TPN = F / 4;
  int tid = blockIdx.x * blockDim.x + threadIdx.x;
  int n = tid / TPN;
  if (n >= N) return;
  int off = (tid % TPN) * 4;
  float4 acc = *reinterpret_cast<const float4*>(ts + (size_t)n * F + off);  // self term
  int j0 = rp[n], j1 = rp[n + 1];
#pragma unroll 4
  for (int j = j0; j < j1; ++j) {
    int s = csr[j];
    const float4 v = *reinterpret_cast<const float4*>(ts + (size_t)s * F + off);
    acc.x += v.x;
    acc.y += v.y;
    acc.z += v.z;
    acc.w += v.w;
  }
  float dn = dis[n];
  float4 o;
  o.x = dn * acc.x;
  o.y = dn * acc.y;
  o.z = dn * acc.z;
  o.w = dn * acc.w;
  *reinterpret_cast<float4*>(outp + (size_t)n * F + off) = o;
}

// ---------------- dense transforms ----------------

template <int FIN, int FOUT, bool RELU, bool SCALE>
__global__ void mlp_kernel(const float* __restrict__ h, const float* __restrict__ W,
                           const float* __restrict__ b, const float* __restrict__ dis,
                           float* __restrict__ t, int N) {
  constexpr int NPB = 256 / FOUT;
  __shared__ float hs[NPB * FIN];
  int nb = blockIdx.x * NPB;
  for (int i = threadIdx.x; i < NPB * FIN; i += 256) {
    int nn = nb + i / FIN;
    hs[i] = (nn < N) ? h[(size_t)nb * FIN + i] : 0.f;
  }
  __syncthreads();
  int nl = threadIdx.x / FOUT;
  int fo = threadIdx.x % FOUT;
  int n = nb + nl;
  if (n >= N) return;
  float acc = b[fo];
#pragma unroll
  for (int k = 0; k < FIN; ++k) acc += hs[nl * FIN + k] * W[k * FOUT + fo];
  if (RELU) acc = fmaxf(acc, 0.f);
  if (SCALE) acc *= dis[n];
  t[(size_t)n * FOUT + fo] = acc;
}

// layer-3 transform fused with segmented max-pool: h3 never materialized.
// 128 threads (= fo), CH consecutive nodes per block, W3 column in registers.
template <int CH>
__global__ __launch_bounds__(128) void mlp3_pool_kernel(
    const float* __restrict__ a3, const float* __restrict__ W3, const float* __restrict__ b3,
    const int* __restrict__ batch, unsigned* __restrict__ pooled, int N) {
  __shared__ float rows[8][32];
  int t = threadIdx.x;
  float Wreg[32];
#pragma unroll
  for (int k = 0; k < 32; ++k) Wreg[k] = W3[k * 128 + t];
  float bb = b3[t];
  int n0 = blockIdx.x * CH;
  int nend = min(n0 + CH, N);
  int curg = batch[n0];
  float runmax = -INFINITY;
  for (int nb = n0; nb < nend; nb += 8) {
    int m = min(8, nend - nb);
    __syncthreads();
    for (int i = t; i < m * 32; i += 128) rows[i >> 5][i & 31] = a3[(size_t)nb * 32 + i];
    __syncthreads();
#pragma unroll
    for (int r = 0; r < 8; ++r) {
      if (r >= m) break;
      int g = batch[nb + r];
      if (g != curg) {
        atomicMax(&pooled[(size_t)curg * 128 + t], fenc(runmax));
        runmax = -INFINITY;
        curg = g;
      }
      float acc = bb;
#pragma unroll
      for (int k = 0; k < 32; ++k) acc += rows[r][k] * Wreg[k];
      runmax = fmaxf(runmax, acc);
    }
  }
  atomicMax(&pooled[(size_t)curg * 128 + t], fenc(runmax));
}

__global__ void head_kernel(const unsigned* __restrict__ pooled, const float* __restrict__ Wl,
                            const float* __restrict__ bl, float* __restrict__ out, int G) {
  int g = blockIdx.x;
  int t = threadIdx.x;  // 128
  float p = fdec(pooled[(size_t)g * 128 + t]);
  __shared__ float red[128];
  __shared__ float sj[3];
  for (int j = 0; j < 3; ++j) {
    red[t] = p * Wl[t * 3 + j];
    __syncthreads();
    for (int k = 64; k > 0; k >>= 1) {
      if (t < k) red[t] += red[t + k];
      __syncthreads();
    }
    if (t == 0) sj[j] = red[0];
    __syncthreads();
  }
  if (t == 0) {
    float l0 = sj[0] + bl[0], l1 = sj[1] + bl[1], l2 = sj[2] + bl[2];
    float m = fmaxf(l0, fmaxf(l1, l2));
    float lse = logf(expf(l0 - m) + expf(l1 - m) + expf(l2 - m));
    out[g * 3 + 0] = l0 - m - lse;
    out[g * 3 + 1] = l1 - m - lse;
    out[g * 3 + 2] = l2 - m - lse;
  }
}

extern "C" void kernel_launch(void* const* d_in, const int* in_sizes, int n_in,
                              void* d_out, int out_size, void* d_ws, size_t ws_size,
                              hipStream_t stream) {
  const float* x = (const float*)d_in[0];
  const int* ei = (const int*)d_in[1];
  const int* batch = (const int*)d_in[2];
  const float* W1 = (const float*)d_in[3];
  const float* b1 = (const float*)d_in[4];
  const float* W2 = (const float*)d_in[5];
  const float* b2 = (const float*)d_in[6];
  const float* W3 = (const float*)d_in[7];
  const float* b3 = (const float*)d_in[8];
  const float* Wl = (const float*)d_in[9];
  const float* bl = (const float*)d_in[10];
  float* out = (float*)d_out;

  const int N = in_sizes[0] / 2;  // x [N,2]
  const int E = in_sizes[1] / 2;  // edge_index [2,E]
  const int G = out_size / 3;     // logits [G,3]

  const int* src = ei;
  const int* dstp = ei + E;

  const int B = (N + BSZ - 1) / BSZ;  // buckets (<=256 for N<=131072)

  size_t NP = ((size_t)N + 256) & ~(size_t)255;
  size_t EP = ((size_t)E + 255) & ~(size_t)255;

  float* dis = (float*)d_ws;               // NP
  int* rp = (int*)d_ws + NP;               // NP
  int* csr = rp + NP;                      // EP
  unsigned* part = (unsigned*)(csr + EP);  // EP
  int* bucketBase = (int*)(part + EP);     // 512 (uses B+1)
  int* bucketCursor = bucketBase + 512;    // 512
  int* bucketCount = bucketCursor + 512;   // 512
  float* arena = (float*)(bucketCount + 512);

  float* a1 = arena;                    // N*2
  float* a2 = arena + (size_t)2 * N;    // N*8
  float* a3 = arena + (size_t)10 * N;   // N*32
  float* h1s = arena + (size_t)42 * N;  // N*8
  float* h2s = arena + (size_t)50 * N;  // N*32
  unsigned* pooled = (unsigned*)(arena + (size_t)82 * N);  // G*128

  const int BS = 256;
  auto cdiv = [](long long a, long long b) { return (int)((a + b - 1) / b); };

  // ---- CSR build (bucketed counting sort)
  hipMemsetAsync(bucketCount, 0, 512 * 4, stream);
  hipMemsetAsync(pooled, 0, (size_t)G * 128 * 4, stream);
  p1_hist_kernel<<<256, 256, 0, stream>>>(dstp, bucketCount, E);
  p1_scan_kernel<<<1, 256, 0, stream>>>(bucketCount, bucketBase, bucketCursor, B, E);
  p2_partition_kernel<<<cdiv(E, P2_TILE), 256, 0, stream>>>(src, dstp, bucketCursor, part, E);
  p3_build_kernel<<<B, BSZ, 0, stream>>>(part, bucketBase, dis, rp, csr, N, B, E);

  // ---- layer 1: agg(F=2) then 2->8 relu, dis-scaled
  agg2_kernel<<<cdiv(N, BS), BS, 0, stream>>>(rp, csr, dis, x, a1, N);
  mlp_kernel<2, 8, true, true><<<cdiv(N, 32), 256, 0, stream>>>(a1, W1, b1, dis, h1s, N);

  // ---- layer 2: agg(F=8) then 8->32 relu, dis-scaled
  agg_vec_kernel<8><<<cdiv((long long)N * 2, BS), BS, 0, stream>>>(rp, csr, dis, h1s, a2, N);
  mlp_kernel<8, 32, true, true><<<cdiv(N, 8), 256, 0, stream>>>(a2, W2, b2, dis, h2s, N);

  // ---- layer 3: agg(F=32), then fused 32->128 + segment-max pool
  agg_vec_kernel<32><<<cdiv((long long)N * 8, BS), BS, 0, stream>>>(rp, csr, dis, h2s, a3, N);
  mlp3_pool_kernel<64><<<cdiv(N, 64), 128, 0, stream>>>(a3, W3, b3, batch, pooled, N);

  // ---- head
  head_kernel<<<G, 128, 0, stream>>>(pooled, Wl, bl, out, G);
}

// Round 5
// 160.488 us; speedup vs baseline: 25.0626x; 1.0231x over previous
//
#include <hip/hip_runtime.h>

// 3-layer GCN, input-dim aggregation (A(XW) = (AX)W), bucketed CSR build,
// per-layer fusion (gather + matvec + bias + relu + dis-prescale in one kernel).
//
// CSR build: counting-sort edges by dst in 512-node buckets.
//   p1_hist: per-block bucket histograms (no global atomics, no memset)
//   p1_scan: reduce + scan -> bucket bases/cursors; also zeroes `pooled`
//   p2:      partition edges into buckets, LDS-ordered coalesced writes
//   p3:      per-bucket local hist -> dis, rp; local scatter -> csr (L2-local)
// Layers:
//   layer1: a1 = A_norm x (regs), h1s = dis*relu(a1 W1 + b1)          [N,8]
//   layer2: a2 = dis*(h1s+sum h1s[nbr]) (regs), h2s = dis*relu(a2 W2+b2) [N,32]
//   agg32 : a3 = dis*(h2s+sum h2s[nbr])                               [N,32]
//   mlp3_pool: h3 = a3 W3 + b3 fused with segment_max (h3 never materialized)
//   head  : log_softmax(pooled Wl + bl)

#define BSHIFT 9
#define BSZ 512
#define P2_TILE 4096
#define P1_BLOCKS 128

__device__ __forceinline__ unsigned fenc(float x) {
  unsigned b = __float_as_uint(x);
  return (b & 0x80000000u) ? ~b : (b | 0x80000000u);
}
__device__ __forceinline__ float fdec(unsigned k) {
  return (k & 0x80000000u) ? __uint_as_float(k ^ 0x80000000u)
                           : __uint_as_float(~k);
}

// ---------------- CSR build ----------------

__global__ __launch_bounds__(256) void p1_hist_kernel(const int* __restrict__ dst,
                                                      int* __restrict__ hist2d, int E) {
  __shared__ int h[256];
  h[threadIdx.x] = 0;
  __syncthreads();
  for (int e = blockIdx.x * blockDim.x + threadIdx.x; e < E; e += gridDim.x * blockDim.x)
    atomicAdd(&h[dst[e] >> BSHIFT], 1);
  __syncthreads();
  hist2d[blockIdx.x * 256 + threadIdx.x] = h[threadIdx.x];
}

__global__ __launch_bounds__(256) void p1_scan_kernel(const int* __restrict__ hist2d,
                                                      int* __restrict__ bucketBase,
                                                      int* __restrict__ bucketCursor,
                                                      unsigned* __restrict__ pooled,
                                                      int B, int E, int G) {
  __shared__ int s[256];
  int t = threadIdx.x;
  int v = 0;
  for (int b = 0; b < P1_BLOCKS; ++b) v += hist2d[b * 256 + t];
  if (t >= B) v = 0;
  s[t] = v;
  __syncthreads();
  for (int o = 1; o < 256; o <<= 1) {
    int u = (t >= o) ? s[t - o] : 0;
    __syncthreads();
    s[t] += u;
    __syncthreads();
  }
  int excl = s[t] - v;
  bucketBase[t] = excl;
  bucketCursor[t] = excl;
  if (t == 0) bucketBase[256] = E;
  // zero the pooled accumulator (fenc key 0 == below -inf)
  for (int i = t; i < G * 128; i += 256) pooled[i] = 0u;
}

__global__ __launch_bounds__(256) void p2_partition_kernel(
    const int* __restrict__ src, const int* __restrict__ dst,
    int* __restrict__ bucketCursor, unsigned* __restrict__ part, int E) {
  __shared__ int hist[256];
  __shared__ int lbase[256];
  __shared__ int gbase[256];
  __shared__ int cur[256];
  __shared__ unsigned sbuf[P2_TILE];
  __shared__ unsigned abuf[P2_TILE];
  int t = threadIdx.x;
  int e0 = blockIdx.x * P2_TILE;
  int cnt = min(P2_TILE, E - e0);

  hist[t] = 0;
  __syncthreads();

  int myb[16];
  unsigned myp[16];
#pragma unroll
  for (int k = 0; k < 16; ++k) {
    int i = t + k * 256;
    if (i < cnt) {
      int e = e0 + i;
      int d = dst[e];
      int b = d >> BSHIFT;
      myb[k] = b;
      myp[k] = ((unsigned)(d & (BSZ - 1)) << 17) | (unsigned)src[e];
      atomicAdd(&hist[b], 1);
    } else {
      myb[k] = -1;
      myp[k] = 0;
    }
  }
  __syncthreads();

  int v = hist[t];
  lbase[t] = v;
  __syncthreads();
  for (int o = 1; o < 256; o <<= 1) {
    int u = (t >= o) ? lbase[t - o] : 0;
    __syncthreads();
    lbase[t] += u;
    __syncthreads();
  }
  int excl = lbase[t] - v;
  __syncthreads();
  lbase[t] = excl;
  if (v > 0) gbase[t] = atomicAdd(&bucketCursor[t], v);
  cur[t] = 0;
  __syncthreads();

#pragma unroll
  for (int k = 0; k < 16; ++k) {
    int b = myb[k];
    if (b >= 0) {
      int pos = atomicAdd(&cur[b], 1);
      int li = lbase[b] + pos;
      sbuf[li] = myp[k];
      abuf[li] = (unsigned)(gbase[b] + pos);
    }
  }
  __syncthreads();

#pragma unroll
  for (int k = 0; k < 16; ++k) {
    int i = t + k * 256;
    if (i < cnt) part[abuf[i]] = sbuf[i];
  }
}

__global__ __launch_bounds__(512) void p3_build_kernel(
    const unsigned* __restrict__ part, const int* __restrict__ bucketBase,
    float* __restrict__ dis, int* __restrict__ rp, int* __restrict__ csr,
    int N, int B, int E) {
  __shared__ int hist[BSZ];
  __shared__ int scn[BSZ];
  int b = blockIdx.x, t = threadIdx.x;
  int base = bucketBase[b], end = bucketBase[b + 1];
  int cnt = end - base;

  hist[t] = 0;
  __syncthreads();
  for (int i = t; i < cnt; i += BSZ) atomicAdd(&hist[part[base + i] >> 17], 1);
  __syncthreads();

  int v = hist[t];
  scn[t] = v;
  __syncthreads();
  for (int o = 1; o < BSZ; o <<= 1) {
    int u = (t >= o) ? scn[t - o] : 0;
    __syncthreads();
    scn[t] += u;
    __syncthreads();
  }
  int excl = scn[t] - v;

  int n = (b << BSHIFT) + t;
  if (n < N) {
    dis[n] = rsqrtf((float)v + 1.0f);
    rp[n] = base + excl;
  }
  if (b == B - 1 && t == 0) rp[N] = E;

  hist[t] = excl;
  __syncthreads();
  for (int i = t; i < cnt; i += BSZ) {
    unsigned p = part[base + i];
    int pos = atomicAdd(&hist[p >> 17], 1);
    csr[base + pos] = (int)(p & 0x1FFFFu);
  }
}

// ---------------- fused layers ----------------

// layer1: thread-per-node. a1 (2 regs) = A_norm x; h1s = dis*relu(a1 W1 + b1).
__global__ __launch_bounds__(256) void layer1_kernel(
    const int* __restrict__ rp, const int* __restrict__ csr, const float* __restrict__ dis,
    const float* __restrict__ x, const float* __restrict__ W1, const float* __restrict__ b1,
    float* __restrict__ h1s, int N) {
  __shared__ float sW[16];
  __shared__ float sb[8];
  int t = threadIdx.x;
  if (t < 16) sW[t] = W1[t];
  if (t < 8) sb[t] = b1[t];
  __syncthreads();
  int n = blockIdx.x * blockDim.x + t;
  if (n >= N) return;
  float dn = dis[n];
  float2 xn = *reinterpret_cast<const float2*>(x + 2 * (size_t)n);
  float ax = dn * xn.x, ay = dn * xn.y;
  int j0 = rp[n], j1 = rp[n + 1];
#pragma unroll 4
  for (int j = j0; j < j1; ++j) {
    int s = csr[j];
    float w = dis[s];
    float2 xs = *reinterpret_cast<const float2*>(x + 2 * (size_t)s);
    ax += w * xs.x;
    ay += w * xs.y;
  }
  ax *= dn;
  ay *= dn;
  float4 o0, o1;
  float* o = &o0.x;
#pragma unroll
  for (int f = 0; f < 8; ++f)
    o[f] = dn * fmaxf(ax * sW[f] + ay * sW[8 + f] + sb[f], 0.f);
  *reinterpret_cast<float4*>(h1s + (size_t)n * 8) = o0;
  *reinterpret_cast<float4*>(h1s + (size_t)n * 8 + 4) = o1;
}

// layer2: thread-per-node. a2 (8 regs) = dis*(self + sum nbr) of h1s;
// h2s = dis*relu(a2 W2 + b2).
__global__ __launch_bounds__(256) void layer2_kernel(
    const int* __restrict__ rp, const int* __restrict__ csr, const float* __restrict__ dis,
    const float* __restrict__ h1s, const float* __restrict__ W2, const float* __restrict__ b2,
    float* __restrict__ h2s, int N) {
  __shared__ float sW[256];  // [8][32]
  __shared__ float sb[32];
  int t = threadIdx.x;
  sW[t] = W2[t];
  if (t < 32) sb[t] = b2[t];
  __syncthreads();
  int n = blockIdx.x * blockDim.x + t;
  if (n >= N) return;
  float4 a0 = *reinterpret_cast<const float4*>(h1s + (size_t)n * 8);
  float4 a1 = *reinterpret_cast<const float4*>(h1s + (size_t)n * 8 + 4);
  int j0 = rp[n], j1 = rp[n + 1];
#pragma unroll 2
  for (int j = j0; j < j1; ++j) {
    int s = csr[j];
    const float4 v0 = *reinterpret_cast<const float4*>(h1s + (size_t)s * 8);
    const float4 v1 = *reinterpret_cast<const float4*>(h1s + (size_t)s * 8 + 4);
    a0.x += v0.x; a0.y += v0.y; a0.z += v0.z; a0.w += v0.w;
    a1.x += v1.x; a1.y += v1.y; a1.z += v1.z; a1.w += v1.w;
  }
  float dn = dis[n];
  float a2r[8] = {dn * a0.x, dn * a0.y, dn * a0.z, dn * a0.w,
                  dn * a1.x, dn * a1.y, dn * a1.z, dn * a1.w};
#pragma unroll
  for (int fc = 0; fc < 8; ++fc) {  // 4 outputs per chunk
    float4 o;
    o.x = sb[fc * 4 + 0]; o.y = sb[fc * 4 + 1]; o.z = sb[fc * 4 + 2]; o.w = sb[fc * 4 + 3];
#pragma unroll
    for (int k = 0; k < 8; ++k) {
      const float4 w = *reinterpret_cast<const float4*>(&sW[k * 32 + fc * 4]);
      float a = a2r[k];
      o.x += a * w.x; o.y += a * w.y; o.z += a * w.z; o.w += a * w.w;
    }
    o.x = dn * fmaxf(o.x, 0.f);
    o.y = dn * fmaxf(o.y, 0.f);
    o.z = dn * fmaxf(o.z, 0.f);
    o.w = dn * fmaxf(o.w, 0.f);
    *reinterpret_cast<float4*>(h2s + (size_t)n * 32 + fc * 4) = o;
  }
}

// layer3 aggregation: F=32, 8 threads per node (float4 each)
__global__ __launch_bounds__(256) void agg32_kernel(
    const int* __restrict__ rp, const int* __restrict__ csr, const float* __restrict__ dis,
    const float* __restrict__ ts, float* __restrict__ outp, int N) {
  int tid = blockIdx.x * blockDim.x + threadIdx.x;
  int n = tid >> 3;
  if (n >= N) return;
  int off = (tid & 7) * 4;
  float4 acc = *reinterpret_cast<const float4*>(ts + (size_t)n * 32 + off);
  int j0 = rp[n], j1 = rp[n + 1];
#pragma unroll 4
  for (int j = j0; j < j1; ++j) {
    int s = csr[j];
    const float4 v = *reinterpret_cast<const float4*>(ts + (size_t)s * 32 + off);
    acc.x += v.x; acc.y += v.y; acc.z += v.z; acc.w += v.w;
  }
  float dn = dis[n];
  float4 o;
  o.x = dn * acc.x; o.y = dn * acc.y; o.z = dn * acc.z; o.w = dn * acc.w;
  *reinterpret_cast<float4*>(outp + (size_t)n * 32 + off) = o;
}

// layer-3 transform fused with segmented max-pool
template <int CH>
__global__ __launch_bounds__(128) void mlp3_pool_kernel(
    const float* __restrict__ a3, const float* __restrict__ W3, const float* __restrict__ b3,
    const int* __restrict__ batch, unsigned* __restrict__ pooled, int N) {
  __shared__ float rows[8][32];
  int t = threadIdx.x;
  float Wreg[32];
#pragma unroll
  for (int k = 0; k < 32; ++k) Wreg[k] = W3[k * 128 + t];
  float bb = b3[t];
  int n0 = blockIdx.x * CH;
  int nend = min(n0 + CH, N);
  int curg = batch[n0];
  float runmax = -INFINITY;
  for (int nb = n0; nb < nend; nb += 8) {
    int m = min(8, nend - nb);
    __syncthreads();
    for (int i = t; i < m * 32; i += 128) rows[i >> 5][i & 31] = a3[(size_t)nb * 32 + i];
    __syncthreads();
#pragma unroll
    for (int r = 0; r < 8; ++r) {
      if (r >= m) break;
      int g = batch[nb + r];
      if (g != curg) {
        atomicMax(&pooled[(size_t)curg * 128 + t], fenc(runmax));
        runmax = -INFINITY;
        curg = g;
      }
      float acc = bb;
#pragma unroll
      for (int k = 0; k < 32; ++k) acc += rows[r][k] * Wreg[k];
      runmax = fmaxf(runmax, acc);
    }
  }
  atomicMax(&pooled[(size_t)curg * 128 + t], fenc(runmax));
}

__global__ __launch_bounds__(128) void head_kernel(
    const unsigned* __restrict__ pooled, const float* __restrict__ Wl,
    const float* __restrict__ bl, float* __restrict__ out, int G) {
  int g = blockIdx.x;
  int t = threadIdx.x;  // 128
  float p = fdec(pooled[(size_t)g * 128 + t]);
  __shared__ float red[128];
  __shared__ float sj[3];
  for (int j = 0; j < 3; ++j) {
    red[t] = p * Wl[t * 3 + j];
    __syncthreads();
    for (int k = 64; k > 0; k >>= 1) {
      if (t < k) red[t] += red[t + k];
      __syncthreads();
    }
    if (t == 0) sj[j] = red[0];
    __syncthreads();
  }
  if (t == 0) {
    float l0 = sj[0] + bl[0], l1 = sj[1] + bl[1], l2 = sj[2] + bl[2];
    float m = fmaxf(l0, fmaxf(l1, l2));
    float lse = logf(expf(l0 - m) + expf(l1 - m) + expf(l2 - m));
    out[g * 3 + 0] = l0 - m - lse;
    out[g * 3 + 1] = l1 - m - lse;
    out[g * 3 + 2] = l2 - m - lse;
  }
}

extern "C" void kernel_launch(void* const* d_in, const int* in_sizes, int n_in,
                              void* d_out, int out_size, void* d_ws, size_t ws_size,
                              hipStream_t stream) {
  const float* x = (const float*)d_in[0];
  const int* ei = (const int*)d_in[1];
  const int* batch = (const int*)d_in[2];
  const float* W1 = (const float*)d_in[3];
  const float* b1 = (const float*)d_in[4];
  const float* W2 = (const float*)d_in[5];
  const float* b2 = (const float*)d_in[6];
  const float* W3 = (const float*)d_in[7];
  const float* b3 = (const float*)d_in[8];
  const float* Wl = (const float*)d_in[9];
  const float* bl = (const float*)d_in[10];
  float* out = (float*)d_out;

  const int N = in_sizes[0] / 2;  // x [N,2]
  const int E = in_sizes[1] / 2;  // edge_index [2,E]
  const int G = out_size / 3;     // logits [G,3]

  const int* src = ei;
  const int* dstp = ei + E;

  const int B = (N + BSZ - 1) / BSZ;  // <=256 for N<=131072

  size_t NP = ((size_t)N + 256) & ~(size_t)255;
  size_t EP = ((size_t)E + 255) & ~(size_t)255;

  float* dis = (float*)d_ws;                 // NP
  int* rp = (int*)d_ws + NP;                 // NP
  int* csr = rp + NP;                        // EP
  unsigned* part = (unsigned*)(csr + EP);    // EP
  int* bucketBase = (int*)(part + EP);       // 512
  int* bucketCursor = bucketBase + 512;      // 512
  int* hist2d = bucketCursor + 512;          // P1_BLOCKS*256
  float* arena = (float*)(hist2d + P1_BLOCKS * 256);

  float* h1s = arena;                                       // N*8
  float* h2s = arena + (size_t)8 * N;                       // N*32
  float* a3 = arena + (size_t)40 * N;                       // N*32
  unsigned* pooled = (unsigned*)(arena + (size_t)72 * N);   // G*128

  const int BS = 256;
  auto cdiv = [](long long a, long long b) { return (int)((a + b - 1) / b); };

  // ---- CSR build
  p1_hist_kernel<<<P1_BLOCKS, 256, 0, stream>>>(dstp, hist2d, E);
  p1_scan_kernel<<<1, 256, 0, stream>>>(hist2d, bucketBase, bucketCursor, pooled, B, E, G);
  p2_partition_kernel<<<cdiv(E, P2_TILE), 256, 0, stream>>>(src, dstp, bucketCursor, part, E);
  p3_build_kernel<<<B, BSZ, 0, stream>>>(part, bucketBase, dis, rp, csr, N, B, E);

  // ---- fused layers
  layer1_kernel<<<cdiv(N, BS), BS, 0, stream>>>(rp, csr, dis, x, W1, b1, h1s, N);
  layer2_kernel<<<cdiv(N, BS), BS, 0, stream>>>(rp, csr, dis, h1s, W2, b2, h2s, N);
  agg32_kernel<<<cdiv((long long)N * 8, BS), BS, 0, stream>>>(rp, csr, dis, h2s, a3, N);
  mlp3_pool_kernel<64><<<cdiv(N, 64), 128, 0, stream>>>(a3, W3, b3, batch, pooled, N);

  // ---- head
  head_kernel<<<G, 128, 0, stream>>>(pooled, Wl, bl, out, G);
}

// Round 6
// 147.801 us; speedup vs baseline: 27.2139x; 1.0858x over previous
//
#include <hip/hip_runtime.h>

// 3-layer GCN, input-dim aggregation (A(XW) = (AX)W), bucketed CSR build,
// fully fused layers.
//
// CSR build (counting sort by dst, 512-node buckets):
//   p1_hist: per-block bucket histograms (no global atomics / memsets)
//   p1_scan: reduce+scan -> bucket bases/cursors; zeroes `pooled`
//   p2:      partition edges bucket-contiguously (LDS-ordered, coalesced writes)
//   p3:      per-bucket local hist -> dis, rp; local scatter -> csr (L2-local);
//            also writes xs[n] = dis[n]*x[n] (pre-scaled layer-1 source)
// Layers:
//   layer1: a1 = dis*(xs_self + sum xs[nbr]); h1s = dis*relu(a1 W1+b1)  [N,8]
//   layer2: a2 = dis*(h1s_self + sum h1s[nbr]); h2s = dis*relu(a2 W2+b2) [N,32]
//   layer3_pool: a3 = dis*(h2s_self + sum h2s[nbr]) -> LDS;
//                h3 = a3 W3 + b3 fused with segment_max (never materialized)
//   head: log_softmax(pooled Wl + bl)

#define BSHIFT 9
#define BSZ 512
#define P2_TILE 2048
#define P1_BLOCKS 128

__device__ __forceinline__ unsigned fenc(float x) {
  unsigned b = __float_as_uint(x);
  return (b & 0x80000000u) ? ~b : (b | 0x80000000u);
}
__device__ __forceinline__ float fdec(unsigned k) {
  return (k & 0x80000000u) ? __uint_as_float(k ^ 0x80000000u)
                           : __uint_as_float(~k);
}

// ---------------- CSR build ----------------

__global__ __launch_bounds__(256) void p1_hist_kernel(const int* __restrict__ dst,
                                                      int* __restrict__ hist2d, int E) {
  __shared__ int h[256];
  h[threadIdx.x] = 0;
  __syncthreads();
  for (int e = blockIdx.x * blockDim.x + threadIdx.x; e < E; e += gridDim.x * blockDim.x)
    atomicAdd(&h[dst[e] >> BSHIFT], 1);
  __syncthreads();
  hist2d[blockIdx.x * 256 + threadIdx.x] = h[threadIdx.x];
}

__global__ __launch_bounds__(256) void p1_scan_kernel(const int* __restrict__ hist2d,
                                                      int* __restrict__ bucketBase,
                                                      int* __restrict__ bucketCursor,
                                                      unsigned* __restrict__ pooled,
                                                      int B, int E, int G) {
  __shared__ int s[256];
  int t = threadIdx.x;
  int v = 0;
  for (int b = 0; b < P1_BLOCKS; ++b) v += hist2d[b * 256 + t];
  if (t >= B) v = 0;
  s[t] = v;
  __syncthreads();
  for (int o = 1; o < 256; o <<= 1) {
    int u = (t >= o) ? s[t - o] : 0;
    __syncthreads();
    s[t] += u;
    __syncthreads();
  }
  int excl = s[t] - v;
  bucketBase[t] = excl;
  bucketCursor[t] = excl;
  if (t == 0) bucketBase[256] = E;
  for (int i = t; i < G * 128; i += 256) pooled[i] = 0u;  // fenc key 0 < -inf
}

__global__ __launch_bounds__(256) void p2_partition_kernel(
    const int* __restrict__ src, const int* __restrict__ dst,
    int* __restrict__ bucketCursor, unsigned* __restrict__ part, int E) {
  __shared__ int hist[256];
  __shared__ int lbase[256];
  __shared__ int gbase[256];
  __shared__ int cur[256];
  __shared__ unsigned sbuf[P2_TILE];
  __shared__ unsigned abuf[P2_TILE];
  int t = threadIdx.x;
  int e0 = blockIdx.x * P2_TILE;
  int cnt = min(P2_TILE, E - e0);

  hist[t] = 0;
  __syncthreads();

  int myb[P2_TILE / 256];
  unsigned myp[P2_TILE / 256];
#pragma unroll
  for (int k = 0; k < P2_TILE / 256; ++k) {
    int i = t + k * 256;
    if (i < cnt) {
      int e = e0 + i;
      int d = dst[e];
      int b = d >> BSHIFT;
      myb[k] = b;
      myp[k] = ((unsigned)(d & (BSZ - 1)) << 17) | (unsigned)src[e];
      atomicAdd(&hist[b], 1);
    } else {
      myb[k] = -1;
      myp[k] = 0;
    }
  }
  __syncthreads();

  int v = hist[t];
  lbase[t] = v;
  __syncthreads();
  for (int o = 1; o < 256; o <<= 1) {
    int u = (t >= o) ? lbase[t - o] : 0;
    __syncthreads();
    lbase[t] += u;
    __syncthreads();
  }
  int excl = lbase[t] - v;
  __syncthreads();
  lbase[t] = excl;
  if (v > 0) gbase[t] = atomicAdd(&bucketCursor[t], v);
  cur[t] = 0;
  __syncthreads();

#pragma unroll
  for (int k = 0; k < P2_TILE / 256; ++k) {
    int b = myb[k];
    if (b >= 0) {
      int pos = atomicAdd(&cur[b], 1);
      int li = lbase[b] + pos;
      sbuf[li] = myp[k];
      abuf[li] = (unsigned)(gbase[b] + pos);
    }
  }
  __syncthreads();

#pragma unroll
  for (int k = 0; k < P2_TILE / 256; ++k) {
    int i = t + k * 256;
    if (i < cnt) part[abuf[i]] = sbuf[i];
  }
}

__global__ __launch_bounds__(512) void p3_build_kernel(
    const unsigned* __restrict__ part, const int* __restrict__ bucketBase,
    const float* __restrict__ x, float* __restrict__ xs,
    float* __restrict__ dis, int* __restrict__ rp, int* __restrict__ csr,
    int N, int B, int E) {
  __shared__ int hist[BSZ];
  __shared__ int scn[BSZ];
  int b = blockIdx.x, t = threadIdx.x;
  int base = bucketBase[b], end = bucketBase[b + 1];
  int cnt = end - base;

  hist[t] = 0;
  __syncthreads();
  for (int i = t; i < cnt; i += BSZ) atomicAdd(&hist[part[base + i] >> 17], 1);
  __syncthreads();

  int v = hist[t];
  scn[t] = v;
  __syncthreads();
  for (int o = 1; o < BSZ; o <<= 1) {
    int u = (t >= o) ? scn[t - o] : 0;
    __syncthreads();
    scn[t] += u;
    __syncthreads();
  }
  int excl = scn[t] - v;

  int n = (b << BSHIFT) + t;
  if (n < N) {
    float dn = rsqrtf((float)v + 1.0f);
    dis[n] = dn;
    rp[n] = base + excl;
    float2 xn = *reinterpret_cast<const float2*>(x + 2 * (size_t)n);
    float2 o;
    o.x = dn * xn.x;
    o.y = dn * xn.y;
    *reinterpret_cast<float2*>(xs + 2 * (size_t)n) = o;
  }
  if (b == B - 1 && t == 0) rp[N] = E;

  hist[t] = excl;
  __syncthreads();
  for (int i = t; i < cnt; i += BSZ) {
    unsigned p = part[base + i];
    int pos = atomicAdd(&hist[p >> 17], 1);
    csr[base + pos] = (int)(p & 0x1FFFFu);
  }
}

// ---------------- fused layers ----------------

// layer1: thread-per-node. acc = xs[n] + sum xs[s]; h1s = dis*relu(dis*acc W1 + b1)
__global__ __launch_bounds__(256) void layer1_kernel(
    const int* __restrict__ rp, const int* __restrict__ csr, const float* __restrict__ dis,
    const float* __restrict__ xs, const float* __restrict__ W1, const float* __restrict__ b1,
    float* __restrict__ h1s, int N) {
  __shared__ float sW[16];
  __shared__ float sb[8];
  int t = threadIdx.x;
  if (t < 16) sW[t] = W1[t];
  if (t < 8) sb[t] = b1[t];
  __syncthreads();
  int n = blockIdx.x * blockDim.x + t;
  if (n >= N) return;
  float2 a = *reinterpret_cast<const float2*>(xs + 2 * (size_t)n);  // self
  int j0 = rp[n], j1 = rp[n + 1];
#pragma unroll 4
  for (int j = j0; j < j1; ++j) {
    int s = csr[j];
    const float2 v = *reinterpret_cast<const float2*>(xs + 2 * (size_t)s);
    a.x += v.x;
    a.y += v.y;
  }
  float dn = dis[n];
  float ax = dn * a.x, ay = dn * a.y;
  float4 o0, o1;
  float* o = &o0.x;
#pragma unroll
  for (int f = 0; f < 8; ++f)
    o[f] = dn * fmaxf(ax * sW[f] + ay * sW[8 + f] + sb[f], 0.f);
  *reinterpret_cast<float4*>(h1s + (size_t)n * 8) = o0;
  *reinterpret_cast<float4*>(h1s + (size_t)n * 8 + 4) = o1;
}

// layer2: thread-per-node, 8-wide register accumulator.
__global__ __launch_bounds__(256) void layer2_kernel(
    const int* __restrict__ rp, const int* __restrict__ csr, const float* __restrict__ dis,
    const float* __restrict__ h1s, const float* __restrict__ W2, const float* __restrict__ b2,
    float* __restrict__ h2s, int N) {
  __shared__ float sW[256];  // [8][32]
  __shared__ float sb[32];
  int t = threadIdx.x;
  sW[t] = W2[t];
  if (t < 32) sb[t] = b2[t];
  __syncthreads();
  int n = blockIdx.x * blockDim.x + t;
  if (n >= N) return;
  float4 a0 = *reinterpret_cast<const float4*>(h1s + (size_t)n * 8);
  float4 a1 = *reinterpret_cast<const float4*>(h1s + (size_t)n * 8 + 4);
  int j0 = rp[n], j1 = rp[n + 1];
#pragma unroll 2
  for (int j = j0; j < j1; ++j) {
    int s = csr[j];
    const float4 v0 = *reinterpret_cast<const float4*>(h1s + (size_t)s * 8);
    const float4 v1 = *reinterpret_cast<const float4*>(h1s + (size_t)s * 8 + 4);
    a0.x += v0.x; a0.y += v0.y; a0.z += v0.z; a0.w += v0.w;
    a1.x += v1.x; a1.y += v1.y; a1.z += v1.z; a1.w += v1.w;
  }
  float dn = dis[n];
  float a2r[8] = {dn * a0.x, dn * a0.y, dn * a0.z, dn * a0.w,
                  dn * a1.x, dn * a1.y, dn * a1.z, dn * a1.w};
#pragma unroll
  for (int fc = 0; fc < 8; ++fc) {
    float4 o;
    o.x = sb[fc * 4 + 0]; o.y = sb[fc * 4 + 1]; o.z = sb[fc * 4 + 2]; o.w = sb[fc * 4 + 3];
#pragma unroll
    for (int k = 0; k < 8; ++k) {
      const float4 w = *reinterpret_cast<const float4*>(&sW[k * 32 + fc * 4]);
      float a = a2r[k];
      o.x += a * w.x; o.y += a * w.y; o.z += a * w.z; o.w += a * w.w;
    }
    o.x = dn * fmaxf(o.x, 0.f);
    o.y = dn * fmaxf(o.y, 0.f);
    o.z = dn * fmaxf(o.z, 0.f);
    o.w = dn * fmaxf(o.w, 0.f);
    *reinterpret_cast<float4*>(h2s + (size_t)n * 32 + fc * 4) = o;
  }
}

// layer3 fused: gather a3 into LDS (8 threads/node, 16 nodes/block), then
// h3 = a3 W3 + b3 with thread-per-feature, fused segmented max-pool.
__global__ __launch_bounds__(128) void layer3_pool_kernel(
    const int* __restrict__ rp, const int* __restrict__ csr, const float* __restrict__ dis,
    const float* __restrict__ h2s, const float* __restrict__ W3, const float* __restrict__ b3,
    const int* __restrict__ batch, unsigned* __restrict__ pooled, int N) {
  __shared__ float rows[16][32];
  int t = threadIdx.x;
  float Wreg[32];
#pragma unroll
  for (int k = 0; k < 32; ++k) Wreg[k] = W3[k * 128 + t];
  float bb = b3[t];

  int n0 = blockIdx.x * 16;
  int m = min(16, N - n0);

  // gather phase: 8 threads per node
  {
    int r = t >> 3;
    int n = n0 + r;
    if (r < m) {
      int off = (t & 7) * 4;
      float4 acc = *reinterpret_cast<const float4*>(h2s + (size_t)n * 32 + off);  // self
      int j0 = rp[n], j1 = rp[n + 1];
#pragma unroll 4
      for (int j = j0; j < j1; ++j) {
        int s = csr[j];
        const float4 v = *reinterpret_cast<const float4*>(h2s + (size_t)s * 32 + off);
        acc.x += v.x; acc.y += v.y; acc.z += v.z; acc.w += v.w;
      }
      float dn = dis[n];
      rows[r][off + 0] = dn * acc.x;
      rows[r][off + 1] = dn * acc.y;
      rows[r][off + 2] = dn * acc.z;
      rows[r][off + 3] = dn * acc.w;
    }
  }
  __syncthreads();

  // matvec + segmented max phase: thread t owns output feature t
  int curg = batch[n0];
  float runmax = -INFINITY;
  for (int r = 0; r < m; ++r) {
    int g = batch[n0 + r];
    if (g != curg) {
      atomicMax(&pooled[(size_t)curg * 128 + t], fenc(runmax));
      runmax = -INFINITY;
      curg = g;
    }
    float acc = bb;
#pragma unroll
    for (int k = 0; k < 32; ++k) acc += rows[r][k] * Wreg[k];
    runmax = fmaxf(runmax, acc);
  }
  atomicMax(&pooled[(size_t)curg * 128 + t], fenc(runmax));
}

__global__ __launch_bounds__(128) void head_kernel(
    const unsigned* __restrict__ pooled, const float* __restrict__ Wl,
    const float* __restrict__ bl, float* __restrict__ out, int G) {
  int g = blockIdx.x;
  int t = threadIdx.x;  // 128
  float p = fdec(pooled[(size_t)g * 128 + t]);
  __shared__ float red[128];
  __shared__ float sj[3];
  for (int j = 0; j < 3; ++j) {
    red[t] = p * Wl[t * 3 + j];
    __syncthreads();
    for (int k = 64; k > 0; k >>= 1) {
      if (t < k) red[t] += red[t + k];
      __syncthreads();
    }
    if (t == 0) sj[j] = red[0];
    __syncthreads();
  }
  if (t == 0) {
    float l0 = sj[0] + bl[0], l1 = sj[1] + bl[1], l2 = sj[2] + bl[2];
    float m = fmaxf(l0, fmaxf(l1, l2));
    float lse = logf(expf(l0 - m) + expf(l1 - m) + expf(l2 - m));
    out[g * 3 + 0] = l0 - m - lse;
    out[g * 3 + 1] = l1 - m - lse;
    out[g * 3 + 2] = l2 - m - lse;
  }
}

extern "C" void kernel_launch(void* const* d_in, const int* in_sizes, int n_in,
                              void* d_out, int out_size, void* d_ws, size_t ws_size,
                              hipStream_t stream) {
  const float* x = (const float*)d_in[0];
  const int* ei = (const int*)d_in[1];
  const int* batch = (const int*)d_in[2];
  const float* W1 = (const float*)d_in[3];
  const float* b1 = (const float*)d_in[4];
  const float* W2 = (const float*)d_in[5];
  const float* b2 = (const float*)d_in[6];
  const float* W3 = (const float*)d_in[7];
  const float* b3 = (const float*)d_in[8];
  const float* Wl = (const float*)d_in[9];
  const float* bl = (const float*)d_in[10];
  float* out = (float*)d_out;

  const int N = in_sizes[0] / 2;  // x [N,2]
  const int E = in_sizes[1] / 2;  // edge_index [2,E]
  const int G = out_size / 3;     // logits [G,3]

  const int* src = ei;
  const int* dstp = ei + E;

  const int B = (N + BSZ - 1) / BSZ;  // <=256 for N<=131072

  size_t NP = ((size_t)N + 256) & ~(size_t)255;
  size_t EP = ((size_t)E + 255) & ~(size_t)255;

  float* dis = (float*)d_ws;                 // NP
  int* rp = (int*)d_ws + NP;                 // NP
  int* csr = rp + NP;                        // EP
  unsigned* part = (unsigned*)(csr + EP);    // EP
  int* bucketBase = (int*)(part + EP);       // 512
  int* bucketCursor = bucketBase + 512;      // 512
  int* hist2d = bucketCursor + 512;          // P1_BLOCKS*256
  float* arena = (float*)(hist2d + P1_BLOCKS * 256);

  float* xs = arena;                                        // N*2
  float* h1s = arena + (size_t)2 * N;                       // N*8
  float* h2s = arena + (size_t)10 * N;                      // N*32
  unsigned* pooled = (unsigned*)(arena + (size_t)42 * N);   // G*128

  const int BS = 256;
  auto cdiv = [](long long a, long long b) { return (int)((a + b - 1) / b); };

  // ---- CSR build
  p1_hist_kernel<<<P1_BLOCKS, 256, 0, stream>>>(dstp, hist2d, E);
  p1_scan_kernel<<<1, 256, 0, stream>>>(hist2d, bucketBase, bucketCursor, pooled, B, E, G);
  p2_partition_kernel<<<cdiv(E, P2_TILE), 256, 0, stream>>>(src, dstp, bucketCursor, part, E);
  p3_build_kernel<<<B, BSZ, 0, stream>>>(part, bucketBase, x, xs, dis, rp, csr, N, B, E);

  // ---- fused layers
  layer1_kernel<<<cdiv(N, BS), BS, 0, stream>>>(rp, csr, dis, xs, W1, b1, h1s, N);
  layer2_kernel<<<cdiv(N, BS), BS, 0, stream>>>(rp, csr, dis, h1s, W2, b2, h2s, N);
  layer3_pool_kernel<<<cdiv(N, 16), 128, 0, stream>>>(rp, csr, dis, h2s, W3, b3, batch, pooled, N);

  // ---- head
  head_kernel<<<G, 128, 0, stream>>>(pooled, Wl, bl, out, G);
}